// Round 11
// baseline (3173.697 us; speedup 1.0000x reference)
//
#include <hip/hip_runtime.h>
#include <hip/hip_fp16.h>

// ============================================================================
// LSTM_78176994722094: 2-layer LSTM (B=128, D_IN=128, T=1024, H=512) + fc head.
//
// R18 = R17 with HIERARCHICAL FLAGS: intra-WG aggregation through LDS, then
// ONE L2 flag per WG (32 per team, 128B = 2 cache lines) instead of one per
// wave (128, 512B = 8 lines).
//
// WHY: R17 landed 3039->2887us (+5%, predicted +20%). Post-mortem: L1's
// "tail" is off the data path but still in each wave's wall-clock round, so
// both teams' serial work is ~1600-2200cy -- yet the measured period is
// ~6770cy. A ~3x latency multiplier sits on every L2 hop. Suspect: flag-poll
// congestion. Every spin iteration each wave loads 512B of flags (8 lines);
// ~256 waves/XCD polling at ~270cy intervals = ~7-8 L2 transactions/cy of
// pure polling on 16 hot lines -- every staging/publish op queues behind it.
// R18 cuts poll traffic 4x (2 lines), flag stores 4x, at the cost of one
// cheap LDS hop on the publish path.
//
// Ordering: each wave sets its LDS done-word only after ITS vmcnt(0) (h
// stores drained to L2); wave0 polls LDS (no L2 traffic) and publishes the
// WG flag; consumers see the flag only after all 4 waves' data landed.
//
// Forensic ledger:
//  R7 4.1ms monolithic | R8/R9 7.9ms hand sc-bits flush L2 | R10 9.9ms no
//  dedup (4x L2 volume) | R12 4.9ms split flags, same-wave-both-layers |
//  R13 4.3ms fragment-order exchange (conflicts 2e8->0) | R15 3.64ms plain
//  loads (atomics ~65cy extra each) | R16 3.04ms role split (L0|L1 teams) |
//  R17 2.89ms L1 pipeline + convoy fixes.
//
// Workspace (<4MB):
//   [0, 16KB)        sync: claim@1024 (8), mode@1040, arrive@1056,
//                    flag0: word 1280 + c*32 + wg (L0 team, 8x32)
//                    flag1: word 1536 + c*32 + wg (L1 team, 8x32)
//   [64KB, 576KB)    h0 exchange: [slot4][cluster8][frag 16KB]
//   [576KB, 832KB)   h1 exchange: [parity2][cluster8][frag 16KB]
//   [832KB, 3904KB)  xTw: [slot3][cluster8][tau32][b16][d128] fp16
// ============================================================================

typedef _Float16 half8 __attribute__((ext_vector_type(8)));
typedef float f32x4 __attribute__((ext_vector_type(4)));
typedef unsigned long long u64;
typedef u64 u64x2 __attribute__((ext_vector_type(2)));

#define MFMA16(a, b, c) __builtin_amdgcn_mfma_f32_16x16x32_f16((a), (b), (c), 0, 0, 0)

#define WS_H0_OFF (64 << 10)
#define WS_H1_OFF (576 << 10)
#define WS_XTW_OFF (832 << 10)
#define SYNC_CLAIM 1024   // 8 u32 (count to 64 each)
#define SYNC_MODE 1040    // 1 u32 (0=undecided, 1=fallback, 2=local)
#define SYNC_ARRIVE 1056  // 1 u32 (count to 512)
#define SYNC_FLAG0 1280   // 8 clusters x 32 u32 (per-WG, L0 team)
#define SYNC_FLAG1 1536   // 8 clusters x 32 u32 (per-WG, L1 team)

__device__ __forceinline__ float sigf(float x) {
  return __builtin_amdgcn_rcpf(1.f + exp2f(-1.44269504f * x));
}
__device__ __forceinline__ float tanhf_(float x) {
  return 1.f - 2.f * __builtin_amdgcn_rcpf(1.f + exp2f(2.88539008f * x));
}
__device__ __forceinline__ unsigned short f2h(float x) {
  _Float16 h = (_Float16)x;  // RNE
  unsigned short b;
  __builtin_memcpy(&b, &h, 2);
  return b;
}
__device__ __forceinline__ u64 lda(const u64* p) {
  return __hip_atomic_load(p, __ATOMIC_RELAXED, __HIP_MEMORY_SCOPE_AGENT);
}
__device__ __forceinline__ unsigned lda32(const unsigned* p) {
  return __hip_atomic_load(p, __ATOMIC_RELAXED, __HIP_MEMORY_SCOPE_AGENT);
}

// split 8 fp32 weights -> hi fp16 + lo fp16 (lo = (w - hi) * 2^11)
__device__ __forceinline__ void cvt_split(const f32x4& a, const f32x4& b,
                                          half8& hi, half8& lo) {
#pragma unroll
  for (int i = 0; i < 4; ++i) {
    float w0 = a[i], w1 = b[i];
    _Float16 h0 = (_Float16)w0, h1 = (_Float16)w1;
    hi[i] = h0;
    hi[i + 4] = h1;
    lo[i] = (_Float16)((w0 - (float)h0) * 2048.0f);
    lo[i + 4] = (_Float16)((w1 - (float)h1) * 2048.0f);
  }
}
// scale a fragment by 2^-11 (exact exponent shift; v_pk_mul_f16)
__device__ __forceinline__ half8 hscale(half8 v) {
  half8 r;
#pragma unroll
  for (int i = 0; i < 8; ++i) r[i] = v[i] * (_Float16)4.8828125e-4f;
  return r;
}

// ---------------------------------------------------------------------------
// Prepass: fill xTw window 0 (t=0..31) slot 0, zero sync area (16KB) and out.
// ---------------------------------------------------------------------------
__global__ void __launch_bounds__(256) prep_kernel(const float* __restrict__ x,
                                                   _Float16* __restrict__ xTw,
                                                   unsigned* __restrict__ sync,
                                                   float* __restrict__ out) {
  const int bid = blockIdx.x;  // 128 = 8c * 16b
  const int c = bid >> 4, b16 = bid & 15;
  const int tid = threadIdx.x;
  if (bid == 0) {
#pragma unroll
    for (int i = 0; i < 16; ++i) sync[i * 256 + tid] = 0;  // 16KB sync area
    out[tid] = 0.f;  // out_size = B*OUT = 256
  }
  const int d = tid & 127, th = tid >> 7;  // th: tau half (0/1)
  const float* src = x + ((size_t)(c * 16 + b16) * 128 + d) * 1024 + th * 16;
  _Float16* dst = xTw + ((size_t)c * 32 + th * 16) * (16 * 128) + b16 * 128 + d;
#pragma unroll
  for (int i = 0; i < 16; ++i) dst[(size_t)i * (16 * 128)] = (_Float16)src[i];
}

// ---------------------------------------------------------------------------
// Persistent scan kernel, role-split + L1 pipeline + hierarchical flags.
// MFMA layouts (verified R1-R17): A[m=lane&15][k=(lane>>4)*8+j],
// B[k][n=lane&15], D[m=(lane>>4)*4+reg][n]. h exchange in MFMA fragment
// order: half (kt,qq,bb,j) holds h[ch=kt*32+qq*8+j][bb].
// ---------------------------------------------------------------------------
__global__ void __launch_bounds__(256, 2) lstm_scan(
    const float* __restrict__ Whh0, const float* __restrict__ bih0,
    const float* __restrict__ bhh0, const float* __restrict__ Wih1,
    const float* __restrict__ Whh1, const float* __restrict__ bih1,
    const float* __restrict__ bhh1, const float* __restrict__ fcW,
    const float* __restrict__ fcb, const float* __restrict__ Wih0,
    const float* __restrict__ x, unsigned* __restrict__ sync,
    unsigned short* __restrict__ exch, _Float16* __restrict__ xTw,
    float* __restrict__ out) {
  // hbuf[0]: L0's h0 stage / L1's h1 stage. hbuf[1],hbuf[2]: L1's h0 parity
  // double-buffer (tail-phase prefetch races the previous round's reads).
  __shared__ __align__(16) _Float16 hbuf[3][16][4][16][8];  // 48KB
  __shared__ unsigned s_bcast[2];
  __shared__ unsigned wdone[4];  // per-wave round counters (intra-WG agg)

  const int tid = threadIdx.x;
  const int wave = tid >> 6;
  const int lane = tid & 63;
  const int q = lane >> 4;
  const int bb = lane & 15;

  // ---- startup: XCD discovery + slot claim + grid barrier + mode decide ----
  unsigned xcc;
  asm("s_getreg_b32 %0, hwreg(HW_REG_XCC_ID)" : "=s"(xcc));
  xcc &= 7;
  unsigned* claim = sync + SYNC_CLAIM;
  unsigned* modew = sync + SYNC_MODE;
  unsigned* arrive = sync + SYNC_ARRIVE;
  if (tid < 4) wdone[tid] = 0;
  if (tid == 0) {
    unsigned idx = __hip_atomic_fetch_add(claim + xcc, 1u, __ATOMIC_RELAXED,
                                          __HIP_MEMORY_SCOPE_AGENT);
    // (idx>>31)==0; data-dependency forces the claim RMW to complete first
    unsigned ord = __hip_atomic_fetch_add(arrive, 1u + (idx >> 31),
                                          __ATOMIC_RELAXED,
                                          __HIP_MEMORY_SCOPE_AGENT);
    if (ord == 511u) {  // last arriver decides for everyone
      unsigned ok = 1;
#pragma unroll
      for (int i = 0; i < 8; ++i)
        ok &= (__hip_atomic_load(claim + i, __ATOMIC_RELAXED,
                                 __HIP_MEMORY_SCOPE_AGENT) == 64u);
      __hip_atomic_store(modew, ok ? 2u : 1u, __ATOMIC_RELAXED,
                         __HIP_MEMORY_SCOPE_AGENT);
    }
    unsigned mv = 0;
    int guard = 0;
    for (;;) {
      mv = __hip_atomic_load(modew, __ATOMIC_RELAXED, __HIP_MEMORY_SCOPE_AGENT);
      if (mv != 0u) break;
      if (++guard > (1 << 18)) { mv = 1u; break; }
    }
    s_bcast[0] = mv;
    s_bcast[1] = idx;
  }
  __syncthreads();
  const bool loc = (s_bcast[0] == 2u);
  const unsigned idx = s_bcast[1];
  bool roleL1;
  int c, wg;
  if (loc) {
    c = (int)xcc;
    roleL1 = idx >= 32u;
    wg = roleL1 ? (int)idx - 32 : (int)idx;
  } else {
    const int b = blockIdx.x;
    roleL1 = b >= 256;
    const int b2 = roleL1 ? b - 256 : b;
    c = b2 >> 5;
    wg = b2 & 31;
  }

  const int wcl = wg * 4 + wave;  // wave id in team: 0..127
  const int chbase = wcl * 4;     // this wave's 4 hidden channels
  const int m = lane & 15;        // A-fragment row id for this lane
  const int arow = (m & 3) * 512 + chbase + (m >> 2);  // i,f,g,o gate order
  unsigned short* xtw16 = (unsigned short*)xTw;
  unsigned short* exch1 = exch + ((512 << 10) >> 1);  // h1 base (ushort)
  const int ch = chbase + q;
  // h publish position (fragment order): ushort offset within a layer block
  const int hoff = (((ch >> 5) * 4 + ((ch >> 3) & 3)) * 16) * 8 + (ch & 7) +
                   bb * 8;

  unsigned* flag0 = sync + SYNC_FLAG0 + c * 32;  // 32 per-WG flags (2 lines)
  unsigned* flag1 = sync + SYNC_FLAG1 + c * 32;
  const unsigned* f0q = flag0 + (lane & 31);
  const unsigned* f1q = flag1 + (lane & 31);
  const int T = 1024;

  // publish helper semantics (inlined below at each site):
  //   vmcnt(0) -> wdone[wave]=r+1 (LDS) -> wave0 polls 4 LDS words ->
  //   wave0/lane0 stores flagX[wg]=r+1 (agent/plain per mode).

  if (!roleL1) {
    // ======================= L0 team: h0 recurrence =======================
    half8 fW0[16], fW0lo[16], fX[4], fXlo[4];
    {
      const float* p0 = Whh0 + (size_t)arow * 512 + q * 8;
#pragma unroll
      for (int kt = 0; kt < 16; ++kt) {
        f32x4 a0 = *(const f32x4*)(p0 + kt * 32),
              b0 = *(const f32x4*)(p0 + kt * 32 + 4);
        cvt_split(a0, b0, fW0[kt], fW0lo[kt]);
      }
      const float* p3 = Wih0 + (size_t)arow * 128 + q * 8;
#pragma unroll
      for (int kt = 0; kt < 4; ++kt) {
        f32x4 a3 = *(const f32x4*)(p3 + kt * 32),
              b3 = *(const f32x4*)(p3 + kt * 32 + 4);
        cvt_split(a3, b3, fX[kt], fXlo[kt]);
      }
    }
    float b0v[4];
#pragma unroll
    for (int g = 0; g < 4; ++g) {
      int rrow = g * 512 + chbase + q;
      b0v[g] = bih0[rrow] + bhh0[rrow];
    }

    float c0 = 0.f;
    for (int r = 0; r < T; ++r) {
      const bool doref = (wave == 2 && r < 992 && (r & 3) == 0);

      // x refresh LOAD only (stores after the publish)
      f32x4 xv4;
      int sw = 0, rw = 0, xb = 0, xd = 0;
      if (doref) {
        const int wnext = (r >> 5) + 1;
        sw = wnext % 3; rw = r & 31;
        xb = wg >> 1; xd = (wg & 1) * 64 + lane;
        xv4 = *(const f32x4*)(x + ((size_t)(c * 16 + xb) * 128 + xd) * 1024 +
                              wnext * 32 + rw);
      }

      // x fragments for t=r (slot written >=32 rounds ago; L1-thrashed)
      half8 xf[4];
      {
        const int s = (r >> 5) % 3, tau = r & 31;
        const u64* xp = (const u64*)xtw16 +
                        (((size_t)(s * 8 + c) * 32 + tau) * 16 + bb) * 32;
        if (loc) {
#pragma unroll
          for (int kt = 0; kt < 4; ++kt)
            xf[kt] =
                __builtin_bit_cast(half8, *(const u64x2*)(xp + kt * 8 + q * 2));
        } else {
#pragma unroll
          for (int kt = 0; kt < 4; ++kt) {
            u64x2 t2;
            t2.x = lda(xp + kt * 8 + q * 2);
            t2.y = lda(xp + kt * 8 + q * 2 + 1);
            xf[kt] = __builtin_bit_cast(half8, t2);
          }
        }
      }

      // accX chain BEFORE the spin (depends only on xf)
      f32x4 accX = {b0v[0], b0v[1], b0v[2], b0v[3]};
#pragma unroll
      for (int kt = 0; kt < 4; ++kt) {
        accX = MFMA16(fX[kt], xf[kt], accX);
        accX = MFMA16(fXlo[kt], hscale(xf[kt]), accX);
      }

      if (r > 0) {
        // spin: own team's h0[r-1] ready AND L1 done with h0[r-4]
        int guard = 0;
        for (;;) {
          unsigned f0 = lda32(f0q), f1 = lda32(f1q);
          bool ok = ((int)f0 >= r) && ((int)f1 >= r - 3);
          if (__ballot(ok) == ~0ull) break;
          if (++guard > 4096) break;  // diagnostic fail-fast, never hangs
        }
        asm volatile("" ::: "memory");  // keep staging below the spin
        // stage h0[r-1] (16KB) from slot (r-1)&3
        if (loc) {
          const u64x2* src =
              (const u64x2*)exch + ((size_t)((r - 1) & 3) * 8 + c) * 1024 + tid;
          u64x2 v[4];
#pragma unroll
          for (int i = 0; i < 4; ++i) v[i] = src[i * 256];
          u64x2* dst = (u64x2*)hbuf[0] + tid;
#pragma unroll
          for (int i = 0; i < 4; ++i) dst[i * 256] = v[i];
        } else {
          const u64* src =
              (const u64*)exch + ((size_t)((r - 1) & 3) * 8 + c) * 2048 + tid;
          u64 v[8];
#pragma unroll
          for (int i = 0; i < 8; ++i) v[i] = lda(src + i * 256);
          u64* dst = (u64*)hbuf[0] + tid;
#pragma unroll
          for (int i = 0; i < 8; ++i) dst[i * 256] = v[i];
        }
      }
      __syncthreads();

      f32x4 a0 = {0.f, 0.f, 0.f, 0.f};
      f32x4 a0b = a0, a0l = a0, a0bl = a0;
      if (r > 0) {
#pragma unroll
        for (int kt = 0; kt < 8; ++kt) {
          half8 hA = *(const half8*)(&hbuf[0][kt][q][bb][0]);
          half8 hB = *(const half8*)(&hbuf[0][kt + 8][q][bb][0]);
          a0 = MFMA16(fW0[kt], hA, a0);
          a0b = MFMA16(fW0[kt + 8], hB, a0b);
          a0l = MFMA16(fW0lo[kt], hscale(hA), a0l);
          a0bl = MFMA16(fW0lo[kt + 8], hscale(hB), a0bl);
        }
      }
      f32x4 g0 = accX + ((a0 + a0b) + (a0l + a0bl));
      float gi = sigf(g0.x), gf = sigf(g0.y), gg = tanhf_(g0.z),
            go = sigf(g0.w);
      c0 = gf * c0 + gi * gg;
      float h0v = go * tanhf_(c0);
      size_t hidx = ((size_t)(r & 3) * 8 + c) * 8192 + hoff;
      if (loc)
        exch[hidx] = f2h(h0v);  // plain -> dirty line in local L2
      else
        __hip_atomic_store(exch + hidx, f2h(h0v), __ATOMIC_RELAXED,
                           __HIP_MEMORY_SCOPE_AGENT);

      // ---- hierarchical publish: vmcnt -> LDS done -> WG flag ----
      asm volatile("s_waitcnt vmcnt(0)" ::: "memory");  // h0 drained
      __hip_atomic_store(&wdone[wave], (unsigned)(r + 1), __ATOMIC_RELAXED,
                         __HIP_MEMORY_SCOPE_WORKGROUP);
      if (wave == 0) {
        int guard = 0;
        for (;;) {
          unsigned w = __hip_atomic_load(&wdone[lane & 3], __ATOMIC_RELAXED,
                                         __HIP_MEMORY_SCOPE_WORKGROUP);
          if (__ballot(w >= (unsigned)(r + 1)) == ~0ull) break;
          if (++guard > 8192) break;
        }
        if (lane == 0) {
          if (loc)
            __hip_atomic_store(flag0 + wg, (unsigned)(r + 1), __ATOMIC_RELAXED,
                               __HIP_MEMORY_SCOPE_WORKGROUP);
          else
            __hip_atomic_store(flag0 + wg, (unsigned)(r + 1), __ATOMIC_RELAXED,
                               __HIP_MEMORY_SCOPE_AGENT);
        }
      }

      // x refresh stores AFTER the publish (off the convoy path)
      if (doref) {
#pragma unroll
        for (int j = 0; j < 4; ++j) {
          size_t xidx =
              (((size_t)(sw * 8 + c) * 32 + rw + j) * 16 + xb) * 128 + xd;
          if (loc)
            xtw16[xidx] = f2h(xv4[j]);
          else
            __hip_atomic_store(xtw16 + xidx, f2h(xv4[j]), __ATOMIC_RELAXED,
                               __HIP_MEMORY_SCOPE_AGENT);
        }
      }
    }
  } else {
    // ========= L1 team: layer 1, software-pipelined behind L0 =========
    half8 fW1i[16], fW1ilo[16], fW1h[16];
    {
      const float* p1 = Wih1 + (size_t)arow * 512 + q * 8;
      const float* p2 = Whh1 + (size_t)arow * 512 + q * 8;
#pragma unroll
      for (int kt = 0; kt < 16; ++kt) {
        f32x4 a1 = *(const f32x4*)(p1 + kt * 32),
              b1 = *(const f32x4*)(p1 + kt * 32 + 4);
        cvt_split(a1, b1, fW1i[kt], fW1ilo[kt]);
        f32x4 a2 = *(const f32x4*)(p2 + kt * 32),
              b2 = *(const f32x4*)(p2 + kt * 32 + 4);
        half8 dummy;
        cvt_split(a2, b2, fW1h[kt], dummy);  // hi only
      }
    }
    float b1v[4];
#pragma unroll
    for (int g = 0; g < 4; ++g) {
      int rrow = g * 512 + chbase + q;
      b1v[g] = bih1[rrow] + bhh1[rrow];
    }
    const float fcw0 = fcW[ch], fcw1 = fcW[512 + ch];

    float c1 = 0.f;
    f32x4 a1 = {b1v[0], b1v[1], b1v[2], b1v[3]};
    f32x4 a1b = {0.f, 0.f, 0.f, 0.f};

    // ---- prologue: a1_pre for t=0 (Wih1 * h0[0], parity buffer 1) ----
    {
      int guard = 0;
      for (;;) {
        unsigned f0 = lda32(f0q);
        bool ok = ((int)f0 >= 1);
        if (__ballot(ok) == ~0ull) break;
        if (++guard > 8192) break;
      }
      asm volatile("" ::: "memory");
      if (loc) {
        const u64x2* src = (const u64x2*)exch + (size_t)c * 1024 + tid;
        u64x2 v[4];
#pragma unroll
        for (int i = 0; i < 4; ++i) v[i] = src[i * 256];
        u64x2* dst = (u64x2*)hbuf[1] + tid;
#pragma unroll
        for (int i = 0; i < 4; ++i) dst[i * 256] = v[i];
      } else {
        const u64* src = (const u64*)exch + (size_t)c * 2048 + tid;
        u64 v[8];
#pragma unroll
        for (int i = 0; i < 8; ++i) v[i] = lda(src + i * 256);
        u64* dst = (u64*)hbuf[1] + tid;
#pragma unroll
        for (int i = 0; i < 8; ++i) dst[i * 256] = v[i];
      }
      __syncthreads();
#pragma unroll
      for (int kt = 0; kt < 8; ++kt) {
        half8 hA = *(const half8*)(&hbuf[1][kt][q][bb][0]);
        half8 hB = *(const half8*)(&hbuf[1][kt + 8][q][bb][0]);
        a1 = MFMA16(fW1i[kt], hA, a1);
        a1b = MFMA16(fW1i[kt + 8], hB, a1b);
        a1 = MFMA16(fW1ilo[kt], hscale(hA), a1);
        a1b = MFMA16(fW1ilo[kt + 8], hscale(hB), a1b);
      }
    }

    for (int t = 0; t < T; ++t) {
      // ---- h1-recurrence segment ----
      if (t > 0) {
        int guard = 0;
        for (;;) {
          unsigned f1 = lda32(f1q);
          bool ok = ((int)f1 >= t);
          if (__ballot(ok) == ~0ull) break;
          if (++guard > 4096) break;
        }
        asm volatile("" ::: "memory");
        // stage h1[t-1] (16KB, parity (t-1)&1) into hbuf[0]
        if (loc) {
          const u64x2* src = (const u64x2*)exch1 +
                             ((size_t)((t - 1) & 1) * 8 + c) * 1024 + tid;
          u64x2 v[4];
#pragma unroll
          for (int i = 0; i < 4; ++i) v[i] = src[i * 256];
          u64x2* dst = (u64x2*)hbuf[0] + tid;
#pragma unroll
          for (int i = 0; i < 4; ++i) dst[i * 256] = v[i];
        } else {
          const u64* src =
              (const u64*)exch1 + ((size_t)((t - 1) & 1) * 8 + c) * 2048 + tid;
          u64 v[8];
#pragma unroll
          for (int i = 0; i < 8; ++i) v[i] = lda(src + i * 256);
          u64* dst = (u64*)hbuf[0] + tid;
#pragma unroll
          for (int i = 0; i < 8; ++i) dst[i * 256] = v[i];
        }
      }
      __syncthreads();

      f32x4 a1c = {0.f, 0.f, 0.f, 0.f};
      f32x4 a1d = a1c;
      if (t > 0) {
#pragma unroll
        for (int kt = 0; kt < 8; ++kt) {
          half8 hC = *(const half8*)(&hbuf[0][kt][q][bb][0]);
          half8 hD = *(const half8*)(&hbuf[0][kt + 8][q][bb][0]);
          a1c = MFMA16(fW1h[kt], hC, a1c);
          a1d = MFMA16(fW1h[kt + 8], hD, a1d);
        }
      }
      f32x4 g1 = (a1 + a1b) + (a1c + a1d);
      float gi = sigf(g1.x), gf = sigf(g1.y), gg = tanhf_(g1.z),
            go = sigf(g1.w);
      c1 = gf * c1 + gi * gg;
      float h1v = go * tanhf_(c1);

      if (t == T - 1) {
        // fc head (out zeroed by prep_kernel each call)
        float s0 = h1v * fcw0, s1 = h1v * fcw1;
        s0 += __shfl_xor(s0, 16); s0 += __shfl_xor(s0, 32);
        s1 += __shfl_xor(s1, 16); s1 += __shfl_xor(s1, 32);
        if (q == 0) {
          atomicAdd(out + (size_t)(c * 16 + bb) * 2 + 0, s0);
          atomicAdd(out + (size_t)(c * 16 + bb) * 2 + 1, s1);
        }
        if (wcl == 0 && lane < 32)
          atomicAdd(out + (size_t)(c * 16 + (lane & 15)) * 2 + (lane >> 4),
                    fcb[lane >> 4]);
      } else {
        size_t hidx = ((size_t)(t & 1) * 8 + c) * 8192 + hoff;
        if (loc)
          exch1[hidx] = f2h(h1v);
        else
          __hip_atomic_store(exch1 + hidx, f2h(h1v), __ATOMIC_RELAXED,
                             __HIP_MEMORY_SCOPE_AGENT);
      }

      // ---- hierarchical publish: vmcnt -> LDS done -> WG flag ----
      asm volatile("s_waitcnt vmcnt(0)" ::: "memory");  // h1 drained
      __hip_atomic_store(&wdone[wave], (unsigned)(t + 1), __ATOMIC_RELAXED,
                         __HIP_MEMORY_SCOPE_WORKGROUP);
      if (wave == 0) {
        int guard = 0;
        for (;;) {
          unsigned w = __hip_atomic_load(&wdone[lane & 3], __ATOMIC_RELAXED,
                                         __HIP_MEMORY_SCOPE_WORKGROUP);
          if (__ballot(w >= (unsigned)(t + 1)) == ~0ull) break;
          if (++guard > 8192) break;
        }
        if (lane == 0) {
          if (loc)
            __hip_atomic_store(flag1 + wg, (unsigned)(t + 1), __ATOMIC_RELAXED,
                               __HIP_MEMORY_SCOPE_WORKGROUP);
          else
            __hip_atomic_store(flag1 + wg, (unsigned)(t + 1), __ATOMIC_RELAXED,
                               __HIP_MEMORY_SCOPE_AGENT);
        }
      }

      // ---- tail: prefetch h0[t+1] + Wih1 chain for next round ----
      if (t < T - 1) {
        int guard = 0;
        for (;;) {
          unsigned f0 = lda32(f0q);
          bool ok = ((int)f0 >= t + 2);
          if (__ballot(ok) == ~0ull) break;
          if (++guard > 4096) break;
        }
        asm volatile("" ::: "memory");
        const int buf = 1 + ((t + 1) & 1);
        if (loc) {
          const u64x2* src = (const u64x2*)exch +
                             ((size_t)((t + 1) & 3) * 8 + c) * 1024 + tid;
          u64x2 v[4];
#pragma unroll
          for (int i = 0; i < 4; ++i) v[i] = src[i * 256];
          u64x2* dst = (u64x2*)hbuf[buf] + tid;
#pragma unroll
          for (int i = 0; i < 4; ++i) dst[i * 256] = v[i];
        } else {
          const u64* src =
              (const u64*)exch + ((size_t)((t + 1) & 3) * 8 + c) * 2048 + tid;
          u64 v[8];
#pragma unroll
          for (int i = 0; i < 8; ++i) v[i] = lda(src + i * 256);
          u64* dst = (u64*)hbuf[buf] + tid;
#pragma unroll
          for (int i = 0; i < 8; ++i) dst[i * 256] = v[i];
        }
        __syncthreads();
        a1 = {b1v[0], b1v[1], b1v[2], b1v[3]};
        a1b = {0.f, 0.f, 0.f, 0.f};
#pragma unroll
        for (int kt = 0; kt < 8; ++kt) {
          half8 hA = *(const half8*)(&hbuf[buf][kt][q][bb][0]);
          half8 hB = *(const half8*)(&hbuf[buf][kt + 8][q][bb][0]);
          a1 = MFMA16(fW1i[kt], hA, a1);
          a1b = MFMA16(fW1i[kt + 8], hB, a1b);
          a1 = MFMA16(fW1ilo[kt], hscale(hA), a1);
          a1b = MFMA16(fW1ilo[kt + 8], hscale(hB), a1b);
        }
      }
    }
  }
}

extern "C" void kernel_launch(void* const* d_in, const int* in_sizes, int n_in,
                              void* d_out, int out_size, void* d_ws,
                              size_t ws_size, hipStream_t stream) {
  const float* x = (const float*)d_in[0];
  const float* Wih0 = (const float*)d_in[1];
  const float* Whh0 = (const float*)d_in[2];
  const float* bih0 = (const float*)d_in[3];
  const float* bhh0 = (const float*)d_in[4];
  const float* Wih1 = (const float*)d_in[5];
  const float* Whh1 = (const float*)d_in[6];
  const float* bih1 = (const float*)d_in[7];
  const float* bhh1 = (const float*)d_in[8];
  const float* fcW = (const float*)d_in[9];
  const float* fcb = (const float*)d_in[10];

  char* ws = (char*)d_ws;  // uses < 4MB total
  unsigned* sync = (unsigned*)ws;
  unsigned short* exch = (unsigned short*)(ws + WS_H0_OFF);
  _Float16* xTw = (_Float16*)(ws + WS_XTW_OFF);
  float* out = (float*)d_out;

  prep_kernel<<<dim3(128), dim3(256), 0, stream>>>(x, xTw, sync, out);
  lstm_scan<<<dim3(512), dim3(256), 0, stream>>>(Whh0, bih0, bhh0, Wih1, Whh1,
                                                 bih1, bhh1, fcW, fcb, Wih0, x,
                                                 sync, exch, xTw, out);
}

// Round 12
// 2895.378 us; speedup vs baseline: 1.0961x; 1.0961x over previous
//
#include <hip/hip_runtime.h>
#include <hip/hip_fp16.h>

// ============================================================================
// LSTM_78176994722094: 2-layer LSTM (B=128, D_IN=128, T=1024, H=512) + fc head.
//
// R19 = R17 (exact revert of R18's hierarchical flags) + NON-TEMPORAL x loads.
//
// R18 post-mortem: hierarchy regressed (2887->3173): wave0's LDS-poll hop
// added serial publish latency; the 4x poll-traffic cut bought nothing ->
// flag-poll congestion REFUTED. The counter that explains the remaining ~2x
// latency multiplier: WRITE_SIZE crept 3.9MB (R15) -> 9MB (R16) -> 22MB
// (R17): streaming x reads (64MB fp32/pass through 4MB/XCD L2) EVICT dirty
// exchange/xTw lines -> staging reads intermittently go to HBM (~900cy vs
// ~270cy) on the recurrence critical path. R19 marks x reads non-temporal
// (nt flag: no L2 LRU displacement); x has zero reuse value. Hot set
// (exchange 96KB + xTw 384KB + weights) stays L2-resident.
//
// Forensic ledger:
//  R7 4.1ms monolithic | R8/R9 7.9ms hand sc-bits flush L2 | R10 9.9ms no
//  dedup (4x L2 volume) | R12 4.9ms split flags same-wave-both-layers |
//  R13 4.3ms fragment-order exchange (conflicts 2e8->0) | R15 3.64ms plain
//  loads | R16 3.04ms role split (L0|L1 teams, 2 blocks/CU) | R17 2.89ms L1
//  pipeline + convoy fixes | R18 3.17ms hierarchical flags REGRESSED.
//
// Workspace (<4MB):
//   [0, 16KB)        sync: claim@1024 (8), mode@1040, arrive@1056,
//                    flag0: word 1280 + c*128 + wcl (L0 team, 8x128)
//                    flag1: word 2304 + c*128 + wcl (L1 team, 8x128)
//   [64KB, 576KB)    h0 exchange: [slot4][cluster8][frag 16KB]
//   [576KB, 832KB)   h1 exchange: [parity2][cluster8][frag 16KB]
//   [832KB, 3904KB)  xTw: [slot3][cluster8][tau32][b16][d128] fp16
// ============================================================================

typedef _Float16 half8 __attribute__((ext_vector_type(8)));
typedef float f32x4 __attribute__((ext_vector_type(4)));
typedef unsigned long long u64;
typedef u64 u64x2 __attribute__((ext_vector_type(2)));

#define MFMA16(a, b, c) __builtin_amdgcn_mfma_f32_16x16x32_f16((a), (b), (c), 0, 0, 0)

#define WS_H0_OFF (64 << 10)
#define WS_H1_OFF (576 << 10)
#define WS_XTW_OFF (832 << 10)
#define SYNC_CLAIM 1024   // 8 u32 (count to 64 each)
#define SYNC_MODE 1040    // 1 u32 (0=undecided, 1=fallback, 2=local)
#define SYNC_ARRIVE 1056  // 1 u32 (count to 512)
#define SYNC_FLAG0 1280   // 8 clusters x 128 u32 (per-wave, L0 team)
#define SYNC_FLAG1 2304   // 8 clusters x 128 u32 (per-wave, L1 team)

__device__ __forceinline__ float sigf(float x) {
  return __builtin_amdgcn_rcpf(1.f + exp2f(-1.44269504f * x));
}
__device__ __forceinline__ float tanhf_(float x) {
  return 1.f - 2.f * __builtin_amdgcn_rcpf(1.f + exp2f(2.88539008f * x));
}
__device__ __forceinline__ unsigned short f2h(float x) {
  _Float16 h = (_Float16)x;  // RNE
  unsigned short b;
  __builtin_memcpy(&b, &h, 2);
  return b;
}
__device__ __forceinline__ u64 lda(const u64* p) {
  return __hip_atomic_load(p, __ATOMIC_RELAXED, __HIP_MEMORY_SCOPE_AGENT);
}
// 16B non-temporal load (nt: no L2 LRU displacement) for the x stream
__device__ __forceinline__ f32x4 ldnt4(const float* p) {
  u64x2 t;
  t.x = __builtin_nontemporal_load((const u64*)p);
  t.y = __builtin_nontemporal_load((const u64*)p + 1);
  return __builtin_bit_cast(f32x4, t);
}

// split 8 fp32 weights -> hi fp16 + lo fp16 (lo = (w - hi) * 2^11)
__device__ __forceinline__ void cvt_split(const f32x4& a, const f32x4& b,
                                          half8& hi, half8& lo) {
#pragma unroll
  for (int i = 0; i < 4; ++i) {
    float w0 = a[i], w1 = b[i];
    _Float16 h0 = (_Float16)w0, h1 = (_Float16)w1;
    hi[i] = h0;
    hi[i + 4] = h1;
    lo[i] = (_Float16)((w0 - (float)h0) * 2048.0f);
    lo[i + 4] = (_Float16)((w1 - (float)h1) * 2048.0f);
  }
}
// scale a fragment by 2^-11 (exact exponent shift; v_pk_mul_f16)
__device__ __forceinline__ half8 hscale(half8 v) {
  half8 r;
#pragma unroll
  for (int i = 0; i < 8; ++i) r[i] = v[i] * (_Float16)4.8828125e-4f;
  return r;
}

// ---------------------------------------------------------------------------
// Prepass: fill xTw window 0 (t=0..31) slot 0, zero sync area (16KB) and out.
// x reads are non-temporal (single use; don't pollute L2).
// ---------------------------------------------------------------------------
__global__ void __launch_bounds__(256) prep_kernel(const float* __restrict__ x,
                                                   _Float16* __restrict__ xTw,
                                                   unsigned* __restrict__ sync,
                                                   float* __restrict__ out) {
  const int bid = blockIdx.x;  // 128 = 8c * 16b
  const int c = bid >> 4, b16 = bid & 15;
  const int tid = threadIdx.x;
  if (bid == 0) {
#pragma unroll
    for (int i = 0; i < 16; ++i) sync[i * 256 + tid] = 0;  // 16KB sync area
    out[tid] = 0.f;  // out_size = B*OUT = 256
  }
  const int d = tid & 127, th = tid >> 7;  // th: tau half (0/1)
  const float* src = x + ((size_t)(c * 16 + b16) * 128 + d) * 1024 + th * 16;
  _Float16* dst = xTw + ((size_t)c * 32 + th * 16) * (16 * 128) + b16 * 128 + d;
#pragma unroll
  for (int i = 0; i < 16; ++i)
    dst[(size_t)i * (16 * 128)] = (_Float16)__builtin_nontemporal_load(src + i);
}

// ---------------------------------------------------------------------------
// Persistent scan kernel, role-split + L1 software pipeline. MFMA layouts
// (verified R1-R18): A[m=lane&15][k=(lane>>4)*8+j], B[k][n=lane&15],
// D[m=(lane>>4)*4+reg][n]. h exchange in MFMA fragment order:
// half (kt,qq,bb,j) holds h[ch=kt*32+qq*8+j][bb].
// ---------------------------------------------------------------------------
__global__ void __launch_bounds__(256, 2) lstm_scan(
    const float* __restrict__ Whh0, const float* __restrict__ bih0,
    const float* __restrict__ bhh0, const float* __restrict__ Wih1,
    const float* __restrict__ Whh1, const float* __restrict__ bih1,
    const float* __restrict__ bhh1, const float* __restrict__ fcW,
    const float* __restrict__ fcb, const float* __restrict__ Wih0,
    const float* __restrict__ x, unsigned* __restrict__ sync,
    unsigned short* __restrict__ exch, _Float16* __restrict__ xTw,
    float* __restrict__ out) {
  // hbuf[0]: L0's h0 stage / L1's h1 stage. hbuf[1],hbuf[2]: L1's h0 parity
  // double-buffer (tail-phase prefetch races the previous round's reads).
  __shared__ __align__(16) _Float16 hbuf[3][16][4][16][8];  // 48KB
  __shared__ unsigned s_bcast[2];

  const int tid = threadIdx.x;
  const int wave = tid >> 6;
  const int lane = tid & 63;
  const int q = lane >> 4;
  const int bb = lane & 15;

  // ---- startup: XCD discovery + slot claim + grid barrier + mode decide ----
  unsigned xcc;
  asm("s_getreg_b32 %0, hwreg(HW_REG_XCC_ID)" : "=s"(xcc));
  xcc &= 7;
  unsigned* claim = sync + SYNC_CLAIM;
  unsigned* modew = sync + SYNC_MODE;
  unsigned* arrive = sync + SYNC_ARRIVE;
  if (tid == 0) {
    unsigned idx = __hip_atomic_fetch_add(claim + xcc, 1u, __ATOMIC_RELAXED,
                                          __HIP_MEMORY_SCOPE_AGENT);
    // (idx>>31)==0; data-dependency forces the claim RMW to complete first
    unsigned ord = __hip_atomic_fetch_add(arrive, 1u + (idx >> 31),
                                          __ATOMIC_RELAXED,
                                          __HIP_MEMORY_SCOPE_AGENT);
    if (ord == 511u) {  // last arriver decides for everyone
      unsigned ok = 1;
#pragma unroll
      for (int i = 0; i < 8; ++i)
        ok &= (__hip_atomic_load(claim + i, __ATOMIC_RELAXED,
                                 __HIP_MEMORY_SCOPE_AGENT) == 64u);
      __hip_atomic_store(modew, ok ? 2u : 1u, __ATOMIC_RELAXED,
                         __HIP_MEMORY_SCOPE_AGENT);
    }
    unsigned mv = 0;
    int guard = 0;
    for (;;) {
      mv = __hip_atomic_load(modew, __ATOMIC_RELAXED, __HIP_MEMORY_SCOPE_AGENT);
      if (mv != 0u) break;
      if (++guard > (1 << 18)) { mv = 1u; break; }
    }
    s_bcast[0] = mv;
    s_bcast[1] = idx;
  }
  __syncthreads();
  const bool loc = (s_bcast[0] == 2u);
  const unsigned idx = s_bcast[1];
  bool roleL1;
  int c, wg;
  if (loc) {
    c = (int)xcc;
    roleL1 = idx >= 32u;
    wg = roleL1 ? (int)idx - 32 : (int)idx;
  } else {
    const int b = blockIdx.x;
    roleL1 = b >= 256;
    const int b2 = roleL1 ? b - 256 : b;
    c = b2 >> 5;
    wg = b2 & 31;
  }

  const int wcl = wg * 4 + wave;  // wave id in team: 0..127
  const int chbase = wcl * 4;     // this wave's 4 hidden channels
  const int m = lane & 15;        // A-fragment row id for this lane
  const int arow = (m & 3) * 512 + chbase + (m >> 2);  // i,f,g,o gate order
  unsigned short* xtw16 = (unsigned short*)xTw;
  unsigned short* exch1 = exch + ((512 << 10) >> 1);  // h1 base (ushort)
  const int ch = chbase + q;
  // h publish position (fragment order): ushort offset within a layer block
  const int hoff = (((ch >> 5) * 4 + ((ch >> 3) & 3)) * 16) * 8 + (ch & 7) +
                   bb * 8;

  unsigned* flag0 = sync + SYNC_FLAG0 + c * 128;
  unsigned* flag1 = sync + SYNC_FLAG1 + c * 128;
  const u64* s0p = (const u64*)flag0 + lane;  // lane polls 2 wave-flags
  const u64* s1p = (const u64*)flag1 + lane;
  const int T = 1024;

  if (!roleL1) {
    // ======================= L0 team: h0 recurrence =======================
    half8 fW0[16], fW0lo[16], fX[4], fXlo[4];
    {
      const float* p0 = Whh0 + (size_t)arow * 512 + q * 8;
#pragma unroll
      for (int kt = 0; kt < 16; ++kt) {
        f32x4 a0 = *(const f32x4*)(p0 + kt * 32),
              b0 = *(const f32x4*)(p0 + kt * 32 + 4);
        cvt_split(a0, b0, fW0[kt], fW0lo[kt]);
      }
      const float* p3 = Wih0 + (size_t)arow * 128 + q * 8;
#pragma unroll
      for (int kt = 0; kt < 4; ++kt) {
        f32x4 a3 = *(const f32x4*)(p3 + kt * 32),
              b3 = *(const f32x4*)(p3 + kt * 32 + 4);
        cvt_split(a3, b3, fX[kt], fXlo[kt]);
      }
    }
    float b0v[4];
#pragma unroll
    for (int g = 0; g < 4; ++g) {
      int rrow = g * 512 + chbase + q;
      b0v[g] = bih0[rrow] + bhh0[rrow];
    }

    float c0 = 0.f;
    for (int r = 0; r < T; ++r) {
      const bool doref = (wave == 2 && r < 992 && (r & 3) == 0);

      // x refresh LOAD only (non-temporal: single-use stream, keep out of
      // L2 LRU; stores after the flag)
      f32x4 xv4;
      int sw = 0, rw = 0, xb = 0, xd = 0;
      if (doref) {
        const int wnext = (r >> 5) + 1;
        sw = wnext % 3; rw = r & 31;
        xb = wg >> 1; xd = (wg & 1) * 64 + lane;
        xv4 = ldnt4(x + ((size_t)(c * 16 + xb) * 128 + xd) * 1024 +
                    wnext * 32 + rw);
      }

      // x fragments for t=r (slot written >=32 rounds ago; L1-thrashed)
      half8 xf[4];
      {
        const int s = (r >> 5) % 3, tau = r & 31;
        const u64* xp = (const u64*)xtw16 +
                        (((size_t)(s * 8 + c) * 32 + tau) * 16 + bb) * 32;
        if (loc) {
#pragma unroll
          for (int kt = 0; kt < 4; ++kt)
            xf[kt] =
                __builtin_bit_cast(half8, *(const u64x2*)(xp + kt * 8 + q * 2));
        } else {
#pragma unroll
          for (int kt = 0; kt < 4; ++kt) {
            u64x2 t2;
            t2.x = lda(xp + kt * 8 + q * 2);
            t2.y = lda(xp + kt * 8 + q * 2 + 1);
            xf[kt] = __builtin_bit_cast(half8, t2);
          }
        }
      }

      // accX chain BEFORE the spin (depends only on xf)
      f32x4 accX = {b0v[0], b0v[1], b0v[2], b0v[3]};
#pragma unroll
      for (int kt = 0; kt < 4; ++kt) {
        accX = MFMA16(fX[kt], xf[kt], accX);
        accX = MFMA16(fXlo[kt], hscale(xf[kt]), accX);
      }

      if (r > 0) {
        // spin: own team's h0[r-1] ready AND L1 done with h0[r-4]
        // (writing slot r&3; flag1 >= r-3 <=> L1 published h1[r-4] and will
        // never again read any h0 older than h0[r-3])
        int guard = 0;
        for (;;) {
          u64 f0 = lda(s0p), f1 = lda(s1p);
          bool ok = ((int)(unsigned)f0 >= r) && ((int)(f0 >> 32) >= r) &&
                    ((int)(unsigned)f1 >= r - 3) && ((int)(f1 >> 32) >= r - 3);
          if (__ballot(ok) == ~0ull) break;
          if (++guard > 4096) break;  // diagnostic fail-fast, never hangs
        }
        asm volatile("" ::: "memory");  // keep staging below the spin
        // stage h0[r-1] (16KB) from slot (r-1)&3
        if (loc) {
          const u64x2* src =
              (const u64x2*)exch + ((size_t)((r - 1) & 3) * 8 + c) * 1024 + tid;
          u64x2 v[4];
#pragma unroll
          for (int i = 0; i < 4; ++i) v[i] = src[i * 256];
          u64x2* dst = (u64x2*)hbuf[0] + tid;
#pragma unroll
          for (int i = 0; i < 4; ++i) dst[i * 256] = v[i];
        } else {
          const u64* src =
              (const u64*)exch + ((size_t)((r - 1) & 3) * 8 + c) * 2048 + tid;
          u64 v[8];
#pragma unroll
          for (int i = 0; i < 8; ++i) v[i] = lda(src + i * 256);
          u64* dst = (u64*)hbuf[0] + tid;
#pragma unroll
          for (int i = 0; i < 8; ++i) dst[i * 256] = v[i];
        }
      }
      __syncthreads();

      f32x4 a0 = {0.f, 0.f, 0.f, 0.f};
      f32x4 a0b = a0, a0l = a0, a0bl = a0;
      if (r > 0) {
#pragma unroll
        for (int kt = 0; kt < 8; ++kt) {
          half8 hA = *(const half8*)(&hbuf[0][kt][q][bb][0]);
          half8 hB = *(const half8*)(&hbuf[0][kt + 8][q][bb][0]);
          a0 = MFMA16(fW0[kt], hA, a0);
          a0b = MFMA16(fW0[kt + 8], hB, a0b);
          a0l = MFMA16(fW0lo[kt], hscale(hA), a0l);
          a0bl = MFMA16(fW0lo[kt + 8], hscale(hB), a0bl);
        }
      }
      f32x4 g0 = accX + ((a0 + a0b) + (a0l + a0bl));
      float gi = sigf(g0.x), gf = sigf(g0.y), gg = tanhf_(g0.z),
            go = sigf(g0.w);
      c0 = gf * c0 + gi * gg;
      float h0v = go * tanhf_(c0);
      size_t hidx = ((size_t)(r & 3) * 8 + c) * 8192 + hoff;
      if (loc)
        exch[hidx] = f2h(h0v);  // plain -> dirty line in local L2
      else
        __hip_atomic_store(exch + hidx, f2h(h0v), __ATOMIC_RELAXED,
                           __HIP_MEMORY_SCOPE_AGENT);

      asm volatile("s_waitcnt vmcnt(0)" ::: "memory");  // h0 drained
      if (lane == 0) {
        if (loc)
          __hip_atomic_store(flag0 + wcl, (unsigned)(r + 1), __ATOMIC_RELAXED,
                             __HIP_MEMORY_SCOPE_WORKGROUP);
        else
          __hip_atomic_store(flag0 + wcl, (unsigned)(r + 1), __ATOMIC_RELAXED,
                             __HIP_MEMORY_SCOPE_AGENT);
      }

      // x refresh stores AFTER the flag (off every wave's convoy path;
      // consumed 32 rounds later, drained by next round's vmcnt(0))
      if (doref) {
#pragma unroll
        for (int j = 0; j < 4; ++j) {
          size_t xidx =
              (((size_t)(sw * 8 + c) * 32 + rw + j) * 16 + xb) * 128 + xd;
          if (loc)
            xtw16[xidx] = f2h(xv4[j]);
          else
            __hip_atomic_store(xtw16 + xidx, f2h(xv4[j]), __ATOMIC_RELAXED,
                               __HIP_MEMORY_SCOPE_AGENT);
        }
      }
    }
  } else {
    // ========= L1 team: layer 1, software-pipelined behind L0 =========
    half8 fW1i[16], fW1ilo[16], fW1h[16];
    {
      const float* p1 = Wih1 + (size_t)arow * 512 + q * 8;
      const float* p2 = Whh1 + (size_t)arow * 512 + q * 8;
#pragma unroll
      for (int kt = 0; kt < 16; ++kt) {
        f32x4 a1 = *(const f32x4*)(p1 + kt * 32),
              b1 = *(const f32x4*)(p1 + kt * 32 + 4);
        cvt_split(a1, b1, fW1i[kt], fW1ilo[kt]);
        f32x4 a2 = *(const f32x4*)(p2 + kt * 32),
              b2 = *(const f32x4*)(p2 + kt * 32 + 4);
        half8 dummy;
        cvt_split(a2, b2, fW1h[kt], dummy);  // hi only
      }
    }
    float b1v[4];
#pragma unroll
    for (int g = 0; g < 4; ++g) {
      int rrow = g * 512 + chbase + q;
      b1v[g] = bih1[rrow] + bhh1[rrow];
    }
    const float fcw0 = fcW[ch], fcw1 = fcW[512 + ch];

    float c1 = 0.f;
    f32x4 a1 = {b1v[0], b1v[1], b1v[2], b1v[3]};
    f32x4 a1b = {0.f, 0.f, 0.f, 0.f};

    // ---- prologue: a1_pre for t=0 (Wih1 * h0[0], parity buffer 1) ----
    {
      int guard = 0;
      for (;;) {
        u64 f0 = lda(s0p);
        bool ok = ((int)(unsigned)f0 >= 1) && ((int)(f0 >> 32) >= 1);
        if (__ballot(ok) == ~0ull) break;
        if (++guard > 8192) break;
      }
      asm volatile("" ::: "memory");
      if (loc) {
        const u64x2* src = (const u64x2*)exch + (size_t)c * 1024 + tid;
        u64x2 v[4];
#pragma unroll
        for (int i = 0; i < 4; ++i) v[i] = src[i * 256];
        u64x2* dst = (u64x2*)hbuf[1] + tid;
#pragma unroll
        for (int i = 0; i < 4; ++i) dst[i * 256] = v[i];
      } else {
        const u64* src = (const u64*)exch + (size_t)c * 2048 + tid;
        u64 v[8];
#pragma unroll
        for (int i = 0; i < 8; ++i) v[i] = lda(src + i * 256);
        u64* dst = (u64*)hbuf[1] + tid;
#pragma unroll
        for (int i = 0; i < 8; ++i) dst[i * 256] = v[i];
      }
      __syncthreads();
#pragma unroll
      for (int kt = 0; kt < 8; ++kt) {
        half8 hA = *(const half8*)(&hbuf[1][kt][q][bb][0]);
        half8 hB = *(const half8*)(&hbuf[1][kt + 8][q][bb][0]);
        a1 = MFMA16(fW1i[kt], hA, a1);
        a1b = MFMA16(fW1i[kt + 8], hB, a1b);
        a1 = MFMA16(fW1ilo[kt], hscale(hA), a1);
        a1b = MFMA16(fW1ilo[kt + 8], hscale(hB), a1b);
      }
    }

    for (int t = 0; t < T; ++t) {
      // ---- h1-recurrence segment (the only work between flag1 stores) ----
      if (t > 0) {
        int guard = 0;
        for (;;) {
          u64 f1 = lda(s1p);
          bool ok = ((int)(unsigned)f1 >= t) && ((int)(f1 >> 32) >= t);
          if (__ballot(ok) == ~0ull) break;
          if (++guard > 4096) break;
        }
        asm volatile("" ::: "memory");
        // stage h1[t-1] (16KB, parity (t-1)&1) into hbuf[0]
        if (loc) {
          const u64x2* src = (const u64x2*)exch1 +
                             ((size_t)((t - 1) & 1) * 8 + c) * 1024 + tid;
          u64x2 v[4];
#pragma unroll
          for (int i = 0; i < 4; ++i) v[i] = src[i * 256];
          u64x2* dst = (u64x2*)hbuf[0] + tid;
#pragma unroll
          for (int i = 0; i < 4; ++i) dst[i * 256] = v[i];
        } else {
          const u64* src =
              (const u64*)exch1 + ((size_t)((t - 1) & 1) * 8 + c) * 2048 + tid;
          u64 v[8];
#pragma unroll
          for (int i = 0; i < 8; ++i) v[i] = lda(src + i * 256);
          u64* dst = (u64*)hbuf[0] + tid;
#pragma unroll
          for (int i = 0; i < 8; ++i) dst[i * 256] = v[i];
        }
      }
      __syncthreads();

      f32x4 a1c = {0.f, 0.f, 0.f, 0.f};
      f32x4 a1d = a1c;
      if (t > 0) {
#pragma unroll
        for (int kt = 0; kt < 8; ++kt) {
          half8 hC = *(const half8*)(&hbuf[0][kt][q][bb][0]);
          half8 hD = *(const half8*)(&hbuf[0][kt + 8][q][bb][0]);
          a1c = MFMA16(fW1h[kt], hC, a1c);
          a1d = MFMA16(fW1h[kt + 8], hD, a1d);
        }
      }
      f32x4 g1 = (a1 + a1b) + (a1c + a1d);
      float gi = sigf(g1.x), gf = sigf(g1.y), gg = tanhf_(g1.z),
            go = sigf(g1.w);
      c1 = gf * c1 + gi * gg;
      float h1v = go * tanhf_(c1);

      if (t == T - 1) {
        // fc head (out zeroed by prep_kernel each call)
        float s0 = h1v * fcw0, s1 = h1v * fcw1;
        s0 += __shfl_xor(s0, 16); s0 += __shfl_xor(s0, 32);
        s1 += __shfl_xor(s1, 16); s1 += __shfl_xor(s1, 32);
        if (q == 0) {
          atomicAdd(out + (size_t)(c * 16 + bb) * 2 + 0, s0);
          atomicAdd(out + (size_t)(c * 16 + bb) * 2 + 1, s1);
        }
        if (wcl == 0 && lane < 32)
          atomicAdd(out + (size_t)(c * 16 + (lane & 15)) * 2 + (lane >> 4),
                    fcb[lane >> 4]);
      } else {
        size_t hidx = ((size_t)(t & 1) * 8 + c) * 8192 + hoff;
        if (loc)
          exch1[hidx] = f2h(h1v);
        else
          __hip_atomic_store(exch1 + hidx, f2h(h1v), __ATOMIC_RELAXED,
                             __HIP_MEMORY_SCOPE_AGENT);
      }
      asm volatile("s_waitcnt vmcnt(0)" ::: "memory");  // h1 drained
      if (lane == 0) {
        if (loc)
          __hip_atomic_store(flag1 + wcl, (unsigned)(t + 1), __ATOMIC_RELAXED,
                             __HIP_MEMORY_SCOPE_WORKGROUP);
        else
          __hip_atomic_store(flag1 + wcl, (unsigned)(t + 1), __ATOMIC_RELAXED,
                             __HIP_MEMORY_SCOPE_AGENT);
      }

      // ---- tail: prefetch h0[t+1] + Wih1 chain for next round (off the
      //      flag1->flag1 serial path; h0[t+1] available via L0's lead) ----
      if (t < T - 1) {
        int guard = 0;
        for (;;) {
          u64 f0 = lda(s0p);
          bool ok = ((int)(unsigned)f0 >= t + 2) && ((int)(f0 >> 32) >= t + 2);
          if (__ballot(ok) == ~0ull) break;
          if (++guard > 4096) break;
        }
        asm volatile("" ::: "memory");
        const int buf = 1 + ((t + 1) & 1);
        if (loc) {
          const u64x2* src = (const u64x2*)exch +
                             ((size_t)((t + 1) & 3) * 8 + c) * 1024 + tid;
          u64x2 v[4];
#pragma unroll
          for (int i = 0; i < 4; ++i) v[i] = src[i * 256];
          u64x2* dst = (u64x2*)hbuf[buf] + tid;
#pragma unroll
          for (int i = 0; i < 4; ++i) dst[i * 256] = v[i];
        } else {
          const u64* src =
              (const u64*)exch + ((size_t)((t + 1) & 3) * 8 + c) * 2048 + tid;
          u64 v[8];
#pragma unroll
          for (int i = 0; i < 8; ++i) v[i] = lda(src + i * 256);
          u64* dst = (u64*)hbuf[buf] + tid;
#pragma unroll
          for (int i = 0; i < 8; ++i) dst[i * 256] = v[i];
        }
        __syncthreads();
        a1 = {b1v[0], b1v[1], b1v[2], b1v[3]};
        a1b = {0.f, 0.f, 0.f, 0.f};
#pragma unroll
        for (int kt = 0; kt < 8; ++kt) {
          half8 hA = *(const half8*)(&hbuf[buf][kt][q][bb][0]);
          half8 hB = *(const half8*)(&hbuf[buf][kt + 8][q][bb][0]);
          a1 = MFMA16(fW1i[kt], hA, a1);
          a1b = MFMA16(fW1i[kt + 8], hB, a1b);
          a1 = MFMA16(fW1ilo[kt], hscale(hA), a1);
          a1b = MFMA16(fW1ilo[kt + 8], hscale(hB), a1b);
        }
      }
    }
  }
}

extern "C" void kernel_launch(void* const* d_in, const int* in_sizes, int n_in,
                              void* d_out, int out_size, void* d_ws,
                              size_t ws_size, hipStream_t stream) {
  const float* x = (const float*)d_in[0];
  const float* Wih0 = (const float*)d_in[1];
  const float* Whh0 = (const float*)d_in[2];
  const float* bih0 = (const float*)d_in[3];
  const float* bhh0 = (const float*)d_in[4];
  const float* Wih1 = (const float*)d_in[5];
  const float* Whh1 = (const float*)d_in[6];
  const float* bih1 = (const float*)d_in[7];
  const float* bhh1 = (const float*)d_in[8];
  const float* fcW = (const float*)d_in[9];
  const float* fcb = (const float*)d_in[10];

  char* ws = (char*)d_ws;  // uses < 4MB total
  unsigned* sync = (unsigned*)ws;
  unsigned short* exch = (unsigned short*)(ws + WS_H0_OFF);
  _Float16* xTw = (_Float16*)(ws + WS_XTW_OFF);
  float* out = (float*)d_out;

  prep_kernel<<<dim3(128), dim3(256), 0, stream>>>(x, xTw, sync, out);
  lstm_scan<<<dim3(512), dim3(256), 0, stream>>>(Whh0, bih0, bhh0, Wih1, Whh1,
                                                 bih1, bhh1, fcW, fcb, Wih0, x,
                                                 sync, exch, xTw, out);
}